// Round 1
// baseline (1171.821 us; speedup 1.0000x reference)
//
#include <hip/hip_runtime.h>
#include <math.h>

// Problem constants
#define MROWS   16384      // B*N = 16*1024
#define KCODES  8192
#define CDIM    256

// d_out layout (floats): [quantized 4194304][loss 1][indices 16384]
#define LOSS_OFF 4194304
#define IDXOFF   4194305

// ws layout (float-sized slots)
#define WS_ENORM 0
#define WS_PVAL  8192                      // 2 * MROWS floats
#define WS_PIDX  (8192 + 2*MROWS)          // 2 * MROWS ints
#define WS_FIDX  (8192 + 4*MROWS)          // MROWS ints

// GEMM tiling
#define BM 64
#define BN 64
#define BK 64
#define NSPLIT 2
#define NTILES ((KCODES / NSPLIT) / BN)    // 64 code tiles per block

// ---------------------------------------------------------------------------
// Kernel 1: ||e_j||^2 for all codes; also zero the loss accumulator slot.
// One wave per code, 4 waves per block.
__global__ void enorm_kernel(const float* __restrict__ emb,
                             float* __restrict__ ws,
                             float* __restrict__ loss_slot) {
    int tid = threadIdx.x;
    int w = tid >> 6, l = tid & 63;
    int j = blockIdx.x * 4 + w;
    const float4* row = (const float4*)(emb + (size_t)j * CDIM);
    float4 v = row[l];
    float s = v.x * v.x + v.y * v.y + v.z * v.z + v.w * v.w;
#pragma unroll
    for (int m = 32; m >= 1; m >>= 1) s += __shfl_xor(s, m, 64);
    if (l == 0) ws[WS_ENORM + j] = s;
    if (blockIdx.x == 0 && tid == 0) *loss_slot = 0.f;
}

// ---------------------------------------------------------------------------
// Kernel 2: fused distance GEMM + running argmin.
// Block: 256 threads (16x16), BM=64 rows x BN=64 codes, K=256 full.
// zs: z tile transposed [k][row] (64 KB). es: E chunk [k][code] (16 KB).
// LDS 80 KB -> 2 blocks/CU. Grid 512 (256 row-blocks x 2 code-splits).
__global__ __launch_bounds__(256, 2)
void vq_argmin_kernel(const float* __restrict__ z,
                      const float* __restrict__ emb,
                      float* __restrict__ ws) {
    __shared__ float zs[CDIM * BM];
    __shared__ float es[BK * BN];

    int tid = threadIdx.x;
    int tx = tid & 15, ty = tid >> 4;
    int rb = blockIdx.x & 255;          // row block
    int sp = blockIdx.x >> 8;           // code split
    int r0 = rb * BM;

    // ---- stage z tile transposed: zs[k*64 + row] ----
    {
        int row = tid & 63;
        int cb = tid >> 6;  // 0..3
        const float4* zg = (const float4*)(z + (size_t)(r0 + row) * CDIM);
#pragma unroll
        for (int j = 0; j < 16; ++j) {
            int c = cb + 4 * j;         // float4 chunk 0..63 along k
            float4 v = zg[c];
            zs[(4 * c + 0) * BM + row] = v.x;
            zs[(4 * c + 1) * BM + row] = v.y;
            zs[(4 * c + 2) * BM + row] = v.z;
            zs[(4 * c + 3) * BM + row] = v.w;
        }
    }

    float rmin[4] = {1e30f, 1e30f, 1e30f, 1e30f};
    int   ridx[4] = {0, 0, 0, 0};
    const float* enorm = ws + WS_ENORM;
    int code_base = sp * (KCODES / NSPLIT);

    for (int tile = 0; tile < NTILES; ++tile) {
        int c0 = code_base + tile * BN;
        float acc[4][4];
#pragma unroll
        for (int i = 0; i < 4; ++i)
#pragma unroll
            for (int j = 0; j < 4; ++j) acc[i][j] = 0.f;

#pragma unroll 1
        for (int kt = 0; kt < CDIM / BK; ++kt) {   // 4 K-chunks
            __syncthreads();
            // stage es[k*64 + code] for k in [kt*64, kt*64+64)
            {
                int code = tid & 63;
                int cb = tid >> 6;  // 0..3
                const float4* eg =
                    (const float4*)(emb + (size_t)(c0 + code) * CDIM + kt * BK);
#pragma unroll
                for (int j = 0; j < 4; ++j) {
                    int c = cb + 4 * j;             // float4 chunk 0..15
                    float4 v = eg[c];
                    es[(4 * c + 0) * BN + code] = v.x;
                    es[(4 * c + 1) * BN + code] = v.y;
                    es[(4 * c + 2) * BN + code] = v.z;
                    es[(4 * c + 3) * BN + code] = v.w;
                }
            }
            __syncthreads();

            const float4* zs4 = (const float4*)zs + (kt * BK) * (BM / 4);
            const float4* es4 = (const float4*)es;
#pragma unroll 4
            for (int k = 0; k < BK; ++k) {
                float4 a = zs4[k * (BM / 4) + ty];
                float4 b = es4[k * (BN / 4) + tx];
                acc[0][0] = fmaf(a.x, b.x, acc[0][0]);
                acc[0][1] = fmaf(a.x, b.y, acc[0][1]);
                acc[0][2] = fmaf(a.x, b.z, acc[0][2]);
                acc[0][3] = fmaf(a.x, b.w, acc[0][3]);
                acc[1][0] = fmaf(a.y, b.x, acc[1][0]);
                acc[1][1] = fmaf(a.y, b.y, acc[1][1]);
                acc[1][2] = fmaf(a.y, b.z, acc[1][2]);
                acc[1][3] = fmaf(a.y, b.w, acc[1][3]);
                acc[2][0] = fmaf(a.z, b.x, acc[2][0]);
                acc[2][1] = fmaf(a.z, b.y, acc[2][1]);
                acc[2][2] = fmaf(a.z, b.z, acc[2][2]);
                acc[2][3] = fmaf(a.z, b.w, acc[2][3]);
                acc[3][0] = fmaf(a.w, b.x, acc[3][0]);
                acc[3][1] = fmaf(a.w, b.y, acc[3][1]);
                acc[3][2] = fmaf(a.w, b.z, acc[3][2]);
                acc[3][3] = fmaf(a.w, b.w, acc[3][3]);
            }
        }

        // per-tile argmin update: score = ||e||^2 - 2*dot (||z||^2 constant)
#pragma unroll
        for (int j = 0; j < 4; ++j) {
            int code = c0 + tx * 4 + j;
            float en = enorm[code];
#pragma unroll
            for (int i = 0; i < 4; ++i) {
                float s = fmaf(-2.f, acc[i][j], en);
                if (s < rmin[i]) { rmin[i] = s; ridx[i] = code; }
            }
        }
    }

    // ---- cross-thread (over tx) argmin reduction via LDS (reuse es) ----
    __syncthreads();
    float* redv = es;                   // [BM][17] padded
    int*   redi = (int*)(es + BM * 17); // [BM][17]; 2*1088 <= 4096 floats ok
#pragma unroll
    for (int i = 0; i < 4; ++i) {
        int row = ty * 4 + i;
        redv[row * 17 + tx] = rmin[i];
        redi[row * 17 + tx] = ridx[i];
    }
    __syncthreads();
    if (tid < 64) {
        float bv = redv[tid * 17];
        int   bi = redi[tid * 17];
        for (int t = 1; t < 16; ++t) {
            float v = redv[tid * 17 + t];
            int   ii = redi[tid * 17 + t];
            if (v < bv || (v == bv && ii < bi)) { bv = v; bi = ii; }
        }
        ws[WS_PVAL + sp * MROWS + r0 + tid] = bv;
        ((int*)ws)[WS_PIDX + sp * MROWS + r0 + tid] = bi;
    }
}

// ---------------------------------------------------------------------------
// Kernel 3: merge the two code-split partials; emit indices (as float).
__global__ void merge_kernel(float* __restrict__ ws,
                             float* __restrict__ out_idx_f) {
    int r = blockIdx.x * 256 + threadIdx.x;   // 0..16383
    float v0 = ws[WS_PVAL + r];
    float v1 = ws[WS_PVAL + MROWS + r];
    int   i0 = ((int*)ws)[WS_PIDX + r];
    int   i1 = ((int*)ws)[WS_PIDX + MROWS + r];
    int   bi = (v1 < v0 || (v1 == v0 && i1 < i0)) ? i1 : i0;
    ((int*)ws)[WS_FIDX + r] = bi;
    out_idx_f[r] = (float)bi;
}

// ---------------------------------------------------------------------------
// Kernel 4: gather quantized vectors, STE output, 1.25*MSE loss.
// One float4 per thread; a wave covers exactly one row (64*4 = 256 dims).
__global__ void quant_loss_kernel(const float* __restrict__ z,
                                  const float* __restrict__ emb,
                                  const float* __restrict__ ws,
                                  float* __restrict__ out) {
    __shared__ float wsum[4];
    int f = blockIdx.x * 256 + threadIdx.x;   // float4 index, 0..1048575
    int row = f >> 6, c4 = f & 63;
    int idx = ((const int*)ws)[WS_FIDX + row];
    float4 q  = ((const float4*)(emb + (size_t)idx * CDIM))[c4];
    float4 zv = ((const float4*)z)[f];
    float dx = q.x - zv.x, dy = q.y - zv.y, dz = q.z - zv.z, dw = q.w - zv.w;
    float4 o;  // match reference STE rounding: z + (q - z)
    o.x = zv.x + dx; o.y = zv.y + dy; o.z = zv.z + dz; o.w = zv.w + dw;
    ((float4*)out)[f] = o;
    float s = dx * dx + dy * dy + dz * dz + dw * dw;
#pragma unroll
    for (int m = 32; m >= 1; m >>= 1) s += __shfl_xor(s, m, 64);
    int lane = threadIdx.x & 63, w = threadIdx.x >> 6;
    if (lane == 0) wsum[w] = s;
    __syncthreads();
    if (threadIdx.x == 0) {
        float t = wsum[0] + wsum[1] + wsum[2] + wsum[3];
        // vq_loss = (1 + 0.25) * mean((q-z)^2)
        atomicAdd(out + LOSS_OFF, t * (1.25f / 4194304.f));
    }
}

// ---------------------------------------------------------------------------
extern "C" void kernel_launch(void* const* d_in, const int* in_sizes, int n_in,
                              void* d_out, int out_size, void* d_ws, size_t ws_size,
                              hipStream_t stream) {
    const float* z   = (const float*)d_in[0];   // (16,1024,256) fp32
    const float* emb = (const float*)d_in[1];   // (8192,256) fp32
    float* out = (float*)d_out;
    float* ws  = (float*)d_ws;                  // needs ~352 KB

    hipLaunchKernelGGL(enorm_kernel, dim3(KCODES / 4), dim3(256), 0, stream,
                       emb, ws, out + LOSS_OFF);
    hipLaunchKernelGGL(vq_argmin_kernel, dim3(256 * NSPLIT), dim3(256), 0, stream,
                       z, emb, ws);
    hipLaunchKernelGGL(merge_kernel, dim3(MROWS / 256), dim3(256), 0, stream,
                       ws, out + IDXOFF);
    hipLaunchKernelGGL(quant_loss_kernel, dim3(MROWS * CDIM / 4 / 256), dim3(256),
                       0, stream, z, emb, ws, out);
}

// Round 2
// 515.355 us; speedup vs baseline: 2.2738x; 2.2738x over previous
//
#include <hip/hip_runtime.h>
#include <math.h>

// Problem constants
#define MROWS   16384      // B*N = 16*1024
#define KCODES  8192
#define CDIM    256

// d_out layout (floats): [quantized 4194304][loss 1][indices 16384]
#define LOSS_OFF 4194304
#define IDXOFF   4194305

// ws layout (float-sized slots)
#define NSPLIT   4
#define NPART    (NSPLIT * 2)              // 4 code splits x 2 wave-columns
#define WS_ENORM 0                         // 8192 floats
#define WS_PVAL  8192                      // NPART * MROWS floats
#define WS_PIDX  (8192 + NPART*MROWS)      // NPART * MROWS ints
#define WS_FIDX  (8192 + 2*NPART*MROWS)    // MROWS ints

// GEMM tiling
#define BM 128
#define BN 128
#define BK 64
#define LDK 72                              // padded k-stride (halves): 144 B rows, 16B aligned, 2-way banks
#define CODES_PER_SPLIT (KCODES / NSPLIT)   // 2048
#define NTILES (CODES_PER_SPLIT / BN)       // 16

typedef float  v4f  __attribute__((ext_vector_type(4)));
typedef _Float16 v8h __attribute__((ext_vector_type(8)));
typedef _Float16 v4h __attribute__((ext_vector_type(4)));

// ---------------------------------------------------------------------------
// Kernel 1: ||e_j||^2 for all codes; also zero the loss accumulator slot.
__global__ void enorm_kernel(const float* __restrict__ emb,
                             float* __restrict__ ws,
                             float* __restrict__ loss_slot) {
    int tid = threadIdx.x;
    int w = tid >> 6, l = tid & 63;
    int j = blockIdx.x * 4 + w;
    const float4* row = (const float4*)(emb + (size_t)j * CDIM);
    float4 v = row[l];
    float s = v.x * v.x + v.y * v.y + v.z * v.z + v.w * v.w;
#pragma unroll
    for (int m = 32; m >= 1; m >>= 1) s += __shfl_xor(s, m, 64);
    if (l == 0) ws[WS_ENORM + j] = s;
    if (blockIdx.x == 0 && tid == 0) *loss_slot = 0.f;
}

// ---------------------------------------------------------------------------
// Kernel 2: split-f16 MFMA distance GEMM + fused argmin.
// Block 256 thr = 4 waves (2x2), block tile 128x128, wave tile 64x64 =
// 4x4 grid of 16x16x32 MFMAs, 3 MFMAs per tile-product (hh, hl, lh).
// LDS: hi/lo planes for z-chunk (128x64) and E-chunk (128x64) + enorm cache.
__global__ __launch_bounds__(256, 2)
void vq_argmin_kernel(const float* __restrict__ z,
                      const float* __restrict__ emb,
                      float* __restrict__ ws) {
    __shared__ _Float16 zsh[BM * LDK];
    __shared__ _Float16 zsl[BM * LDK];
    __shared__ _Float16 esh[BN * LDK];
    __shared__ _Float16 esl[BN * LDK];
    __shared__ float    en_lds[CODES_PER_SPLIT];

    int tid  = threadIdx.x;
    int lane = tid & 63;
    int w    = tid >> 6;          // wave 0..3
    int tm   = lane & 15;         // MFMA m (A) / n (B) index
    int q    = lane >> 4;         // MFMA k-quad
    int wm   = w & 1, wn = w >> 1;
    int m0w  = wm * 64, n0w = wn * 64;

    int rb = blockIdx.x & 127;    // row block 0..127
    int sp = blockIdx.x >> 7;     // code split 0..3
    int r0 = rb * BM;
    int cbase = sp * CODES_PER_SPLIT;

    // cache ||e||^2 for this split (first barrier below makes it visible)
#pragma unroll
    for (int i = 0; i < CODES_PER_SPLIT / 256; ++i)
        en_lds[i * 256 + tid] = ws[WS_ENORM + cbase + i * 256 + tid];

    float rmin[16];
    int   ridx[16];
#pragma unroll
    for (int s = 0; s < 16; ++s) { rmin[s] = 3e38f; ridx[s] = 0; }

    for (int tile = 0; tile < NTILES; ++tile) {
        int c0 = cbase + tile * BN;
        v4f acc[4][4];
#pragma unroll
        for (int i = 0; i < 4; ++i)
#pragma unroll
            for (int j = 0; j < 4; ++j) acc[i][j] = (v4f)0.f;

#pragma unroll 1
        for (int kt = 0; kt < CDIM / BK; ++kt) {
            __syncthreads();
            // ---- stage z-chunk and E-chunk, fp32 -> f16 hi/lo planes ----
#pragma unroll
            for (int i = 0; i < 8; ++i) {
                int f   = i * 256 + tid;       // float4 slot 0..2047
                int row = f >> 4;              // 0..127
                int kq  = f & 15;              // float4 within row
                float4 zv = *(const float4*)(z + (size_t)(r0 + row) * CDIM + kt * BK + kq * 4);
                v4h h, l;
                h.x = (_Float16)zv.x; l.x = (_Float16)(zv.x - (float)h.x);
                h.y = (_Float16)zv.y; l.y = (_Float16)(zv.y - (float)h.y);
                h.z = (_Float16)zv.z; l.z = (_Float16)(zv.z - (float)h.z);
                h.w = (_Float16)zv.w; l.w = (_Float16)(zv.w - (float)h.w);
                *(v4h*)&zsh[row * LDK + kq * 4] = h;
                *(v4h*)&zsl[row * LDK + kq * 4] = l;
                float4 ev = *(const float4*)(emb + (size_t)(c0 + row) * CDIM + kt * BK + kq * 4);
                h.x = (_Float16)ev.x; l.x = (_Float16)(ev.x - (float)h.x);
                h.y = (_Float16)ev.y; l.y = (_Float16)(ev.y - (float)h.y);
                h.z = (_Float16)ev.z; l.z = (_Float16)(ev.z - (float)h.z);
                h.w = (_Float16)ev.w; l.w = (_Float16)(ev.w - (float)h.w);
                *(v4h*)&esh[row * LDK + kq * 4] = h;
                *(v4h*)&esl[row * LDK + kq * 4] = l;
            }
            __syncthreads();

            // ---- MFMA over this K-chunk: 2 microsteps of K=32 ----
#pragma unroll
            for (int kk = 0; kk < BK; kk += 32) {
                v8h ah[4], al[4], bh[4], bl[4];
#pragma unroll
                for (int mi = 0; mi < 4; ++mi) {
                    int off = (m0w + mi * 16 + tm) * LDK + kk + q * 8;
                    ah[mi] = *(const v8h*)&zsh[off];
                    al[mi] = *(const v8h*)&zsl[off];
                }
#pragma unroll
                for (int ni = 0; ni < 4; ++ni) {
                    int off = (n0w + ni * 16 + tm) * LDK + kk + q * 8;
                    bh[ni] = *(const v8h*)&esh[off];
                    bl[ni] = *(const v8h*)&esl[off];
                }
#pragma unroll
                for (int mi = 0; mi < 4; ++mi)
#pragma unroll
                    for (int ni = 0; ni < 4; ++ni) {
                        acc[mi][ni] = __builtin_amdgcn_mfma_f32_16x16x32_f16(ah[mi], bh[ni], acc[mi][ni], 0, 0, 0);
                        acc[mi][ni] = __builtin_amdgcn_mfma_f32_16x16x32_f16(ah[mi], bl[ni], acc[mi][ni], 0, 0, 0);
                        acc[mi][ni] = __builtin_amdgcn_mfma_f32_16x16x32_f16(al[mi], bh[ni], acc[mi][ni], 0, 0, 0);
                    }
            }
        }

        // ---- per-tile argmin update: score = ||e||^2 - 2*dot ----
#pragma unroll
        for (int ni = 0; ni < 4; ++ni) {
            int cl   = tile * BN + n0w + ni * 16 + tm;   // local code in split
            float en = en_lds[cl];
            int code = cbase + cl;
#pragma unroll
            for (int mi = 0; mi < 4; ++mi)
#pragma unroll
                for (int r = 0; r < 4; ++r) {
                    float s = fmaf(-2.f, acc[mi][ni][r], en);
                    int slot = mi * 4 + r;
                    if (s < rmin[slot]) { rmin[slot] = s; ridx[slot] = code; }
                }
        }
    }

    // ---- reduce across the 16 column-lanes (tm) per row ----
#pragma unroll
    for (int slot = 0; slot < 16; ++slot) {
        float bv = rmin[slot];
        int   bi = ridx[slot];
#pragma unroll
        for (int m = 1; m <= 8; m <<= 1) {
            float v2 = __shfl_xor(bv, m, 64);
            int   i2 = __shfl_xor(bi, m, 64);
            if (v2 < bv || (v2 == bv && i2 < bi)) { bv = v2; bi = i2; }
        }
        if (tm == 0) {
            int grow = r0 + m0w + (slot >> 2) * 16 + q * 4 + (slot & 3);
            int part = sp * 2 + wn;
            ws[WS_PVAL + part * MROWS + grow] = bv;
            ((int*)ws)[WS_PIDX + part * MROWS + grow] = bi;
        }
    }
}

// ---------------------------------------------------------------------------
// Kernel 3: merge the NPART partials; emit indices (as float).
__global__ void merge_kernel(float* __restrict__ ws,
                             float* __restrict__ out_idx_f) {
    int r = blockIdx.x * 256 + threadIdx.x;   // 0..16383
    float bv = ws[WS_PVAL + r];
    int   bi = ((int*)ws)[WS_PIDX + r];
#pragma unroll
    for (int p = 1; p < NPART; ++p) {
        float v = ws[WS_PVAL + p * MROWS + r];
        int   i = ((int*)ws)[WS_PIDX + p * MROWS + r];
        if (v < bv || (v == bv && i < bi)) { bv = v; bi = i; }
    }
    ((int*)ws)[WS_FIDX + r] = bi;
    out_idx_f[r] = (float)bi;
}

// ---------------------------------------------------------------------------
// Kernel 4: gather quantized vectors, STE output, 1.25*MSE loss.
__global__ void quant_loss_kernel(const float* __restrict__ z,
                                  const float* __restrict__ emb,
                                  const float* __restrict__ ws,
                                  float* __restrict__ out) {
    __shared__ float wsum[4];
    int f = blockIdx.x * 256 + threadIdx.x;   // float4 index, 0..1048575
    int row = f >> 6, c4 = f & 63;
    int idx = ((const int*)ws)[WS_FIDX + row];
    float4 qv = ((const float4*)(emb + (size_t)idx * CDIM))[c4];
    float4 zv = ((const float4*)z)[f];
    float dx = qv.x - zv.x, dy = qv.y - zv.y, dz = qv.z - zv.z, dw = qv.w - zv.w;
    float4 o;  // match reference STE rounding: z + (q - z)
    o.x = zv.x + dx; o.y = zv.y + dy; o.z = zv.z + dz; o.w = zv.w + dw;
    ((float4*)out)[f] = o;
    float s = dx * dx + dy * dy + dz * dz + dw * dw;
#pragma unroll
    for (int m = 32; m >= 1; m >>= 1) s += __shfl_xor(s, m, 64);
    int lane = threadIdx.x & 63, wv = threadIdx.x >> 6;
    if (lane == 0) wsum[wv] = s;
    __syncthreads();
    if (threadIdx.x == 0) {
        float t = wsum[0] + wsum[1] + wsum[2] + wsum[3];
        atomicAdd(out + LOSS_OFF, t * (1.25f / 4194304.f));
    }
}

// ---------------------------------------------------------------------------
extern "C" void kernel_launch(void* const* d_in, const int* in_sizes, int n_in,
                              void* d_out, int out_size, void* d_ws, size_t ws_size,
                              hipStream_t stream) {
    const float* z   = (const float*)d_in[0];   // (16,1024,256) fp32
    const float* emb = (const float*)d_in[1];   // (8192,256) fp32
    float* out = (float*)d_out;
    float* ws  = (float*)d_ws;                  // ~1.1 MB used

    hipLaunchKernelGGL(enorm_kernel, dim3(KCODES / 4), dim3(256), 0, stream,
                       emb, ws, out + LOSS_OFF);
    hipLaunchKernelGGL(vq_argmin_kernel, dim3((MROWS / BM) * NSPLIT), dim3(256), 0, stream,
                       z, emb, ws);
    hipLaunchKernelGGL(merge_kernel, dim3(MROWS / 256), dim3(256), 0, stream,
                       ws, out + IDXOFF);
    hipLaunchKernelGGL(quant_loss_kernel, dim3(MROWS * CDIM / 4 / 256), dim3(256),
                       0, stream, z, emb, ws, out);
}

// Round 3
// 317.377 us; speedup vs baseline: 3.6922x; 1.6238x over previous
//
#include <hip/hip_runtime.h>
#include <math.h>

// Problem constants
#define MROWS   16384      // B*N
#define KCODES  8192
#define CDIM    256

// d_out layout (floats): [quantized 4194304][loss 1][indices 16384]
#define LOSS_OFF 4194304
#define IDXOFF   4194305

// ---- ws byte layout: pre-split f16 planes + reduction scratch (~26.7 MB) ----
#define NSPLIT  4
#define NPART   (NSPLIT * 2)
#define WS_ZH   0
#define WS_ZL   (WS_ZH + MROWS * CDIM * 2)          // 8.39 MB each
#define WS_EH   (WS_ZL + MROWS * CDIM * 2)
#define WS_EL   (WS_EH + KCODES * CDIM * 2)         // 4.19 MB each
#define WS_EN   (WS_EL + KCODES * CDIM * 2)         // float[8192]
#define WS_PV   (WS_EN + KCODES * 4)                // float[NPART*MROWS]
#define WS_PI   (WS_PV + NPART * MROWS * 4)         // int[NPART*MROWS]
#define WS_FI   (WS_PI + NPART * MROWS * 4)         // int[MROWS]

// GEMM tiling
#define BM 128
#define BN 128
#define BK 64
#define CODES_PER_SPLIT (KCODES / NSPLIT)   // 2048
#define NTILES (CODES_PER_SPLIT / BN)       // 16

typedef float    v4f __attribute__((ext_vector_type(4)));
typedef _Float16 v8h __attribute__((ext_vector_type(8)));
typedef _Float16 v4h __attribute__((ext_vector_type(4)));

__device__ __forceinline__ void gload_lds16(const void* g, void* l) {
    __builtin_amdgcn_global_load_lds(
        (const __attribute__((address_space(1))) void*)g,
        (__attribute__((address_space(3))) void*)l, 16, 0, 0);
}

// ---------------------------------------------------------------------------
// Kernel 0: split fp32 -> f16 hi/lo planes for z and emb (Markidis split).
__global__ void split_kernel(const float* __restrict__ z,
                             const float* __restrict__ emb,
                             char* __restrict__ ws) {
    int t = blockIdx.x * 256 + threadIdx.x;          // float4 index
    const int NZ = MROWS * CDIM / 4;                 // 1048576
    const float4* s4;
    _Float16 *hp, *lp;
    if (t < NZ) {
        s4 = ((const float4*)z) + t;
        hp = (_Float16*)(ws + WS_ZH) + (size_t)t * 4;
        lp = (_Float16*)(ws + WS_ZL) + (size_t)t * 4;
    } else {
        int u = t - NZ;                               // 0 .. KCODES*CDIM/4-1
        s4 = ((const float4*)emb) + u;
        hp = (_Float16*)(ws + WS_EH) + (size_t)u * 4;
        lp = (_Float16*)(ws + WS_EL) + (size_t)u * 4;
    }
    float4 v = *s4;
    v4h h, l;
    h.x = (_Float16)v.x; l.x = (_Float16)(v.x - (float)h.x);
    h.y = (_Float16)v.y; l.y = (_Float16)(v.y - (float)h.y);
    h.z = (_Float16)v.z; l.z = (_Float16)(v.z - (float)h.z);
    h.w = (_Float16)v.w; l.w = (_Float16)(v.w - (float)h.w);
    *(v4h*)hp = h;
    *(v4h*)lp = l;
}

// ---------------------------------------------------------------------------
// Kernel 1: ||e_j||^2 for all codes; also zero the loss accumulator slot.
__global__ void enorm_kernel(const float* __restrict__ emb,
                             char* __restrict__ ws,
                             float* __restrict__ loss_slot) {
    int tid = threadIdx.x;
    int w = tid >> 6, l = tid & 63;
    int j = blockIdx.x * 4 + w;
    const float4* row = (const float4*)(emb + (size_t)j * CDIM);
    float4 v = row[l];
    float s = v.x * v.x + v.y * v.y + v.z * v.z + v.w * v.w;
#pragma unroll
    for (int m = 32; m >= 1; m >>= 1) s += __shfl_xor(s, m, 64);
    if (l == 0) ((float*)(ws + WS_EN))[j] = s;
    if (blockIdx.x == 0 && tid == 0) *loss_slot = 0.f;
}

// ---------------------------------------------------------------------------
// Kernel 2: split-f16 MFMA distance GEMM + fused argmin.
// Staging: global_load_lds (16B) from pre-split planes, XOR-swizzled 16B
// chunks (phys = logical ^ (row&7)) baked into the *source* address so the
// LDS destination stays lane-contiguous (global_load_lds requirement).
__global__ __launch_bounds__(256, 2)
void vq_argmin_kernel(const char* __restrict__ ws_c, char* __restrict__ ws) {
    // per-kt chunk planes: 128 rows x 64 halves (128 B/row), no padding
    __shared__ __align__(16) _Float16 zsh[BM * BK];
    __shared__ __align__(16) _Float16 zsl[BM * BK];
    __shared__ __align__(16) _Float16 esh[BN * BK];
    __shared__ __align__(16) _Float16 esl[BN * BK];
    __shared__ float en_lds[CODES_PER_SPLIT];

    int tid  = threadIdx.x;
    int lane = tid & 63;
    int w    = tid >> 6;          // wave 0..3
    int tm   = lane & 15;         // MFMA m/n index
    int q    = lane >> 4;         // MFMA k-quad
    int wm   = w & 1, wn = w >> 1;
    int m0w  = wm * 64, n0w = wn * 64;

    int rb = blockIdx.x & 127;    // row block
    int sp = blockIdx.x >> 7;     // code split
    int r0 = rb * BM;
    int cbase = sp * CODES_PER_SPLIT;

    // staging role: one wave per plane
    const char* gplane;
    char*       lplane;
    bool isE = (w >= 2);
    if      (w == 0) { gplane = ws_c + WS_ZH; lplane = (char*)zsh; }
    else if (w == 1) { gplane = ws_c + WS_ZL; lplane = (char*)zsl; }
    else if (w == 2) { gplane = ws_c + WS_EH; lplane = (char*)esh; }
    else             { gplane = ws_c + WS_EL; lplane = (char*)esl; }
    // lane -> (row-in-8-row-slab, chunk slot); source carries the XOR swizzle
    int h3 = lane >> 3, s3 = lane & 7;
    int laneoff = h3 * 512 + ((s3 ^ h3) << 4);       // bytes within slab

    // cache ||e||^2 for this split
#pragma unroll
    for (int i = 0; i < CODES_PER_SPLIT / 256; ++i)
        en_lds[i * 256 + tid] = ((const float*)(ws_c + WS_EN))[cbase + i * 256 + tid];

    // fragment read offsets (halves): row*64 + (chunk ^ (tm&7))*8
    int t7 = tm & 7;
    int p0 = (q ^ t7) << 3;           // kk=0  chunk = q
    int p1 = p0 ^ 32;                 // kk=32 chunk = q+4 -> phys ^4 -> +-32 halves
    int abase[4], bbase[4];
#pragma unroll
    for (int i = 0; i < 4; ++i) {
        abase[i] = (m0w + i * 16 + tm) * 64;
        bbase[i] = (n0w + i * 16 + tm) * 64;
    }

    float rmin[16];
    int   ridx[16];
#pragma unroll
    for (int s = 0; s < 16; ++s) { rmin[s] = 3e38f; ridx[s] = 0; }

    for (int tile = 0; tile < NTILES; ++tile) {
        int c0 = cbase + tile * BN;
        v4f acc[4][4];
#pragma unroll
        for (int i = 0; i < 4; ++i)
#pragma unroll
            for (int j = 0; j < 4; ++j) acc[i][j] = (v4f)0.f;

        const char* gsrc0 = gplane + (size_t)(isE ? c0 : r0) * 512 + laneoff;

#pragma unroll 1
        for (int kt = 0; kt < CDIM / BK; ++kt) {
            __syncthreads();
            const char* src = gsrc0 + kt * 128;
#pragma unroll
            for (int i = 0; i < 16; ++i)
                gload_lds16(src + i * 4096, lplane + i * 1024);
            __syncthreads();

#pragma unroll
            for (int kk = 0; kk < 2; ++kk) {
                int pk = kk ? p1 : p0;
                v8h ah[4], al[4], bh[4], bl[4];
#pragma unroll
                for (int mi = 0; mi < 4; ++mi) {
                    int o = abase[mi] + pk;
                    ah[mi] = *(const v8h*)&zsh[o];
                    al[mi] = *(const v8h*)&zsl[o];
                }
#pragma unroll
                for (int ni = 0; ni < 4; ++ni) {
                    int o = bbase[ni] + pk;
                    bh[ni] = *(const v8h*)&esh[o];
                    bl[ni] = *(const v8h*)&esl[o];
                }
#pragma unroll
                for (int mi = 0; mi < 4; ++mi)
#pragma unroll
                    for (int ni = 0; ni < 4; ++ni) {
                        acc[mi][ni] = __builtin_amdgcn_mfma_f32_16x16x32_f16(ah[mi], bh[ni], acc[mi][ni], 0, 0, 0);
                        acc[mi][ni] = __builtin_amdgcn_mfma_f32_16x16x32_f16(ah[mi], bl[ni], acc[mi][ni], 0, 0, 0);
                        acc[mi][ni] = __builtin_amdgcn_mfma_f32_16x16x32_f16(al[mi], bh[ni], acc[mi][ni], 0, 0, 0);
                    }
            }
        }

        // per-tile argmin update: score = ||e||^2 - 2*dot
#pragma unroll
        for (int ni = 0; ni < 4; ++ni) {
            int cl   = tile * BN + n0w + ni * 16 + tm;
            float en = en_lds[cl];
            int code = cbase + cl;
#pragma unroll
            for (int mi = 0; mi < 4; ++mi)
#pragma unroll
                for (int r = 0; r < 4; ++r) {
                    float s = fmaf(-2.f, acc[mi][ni][r], en);
                    int slot = mi * 4 + r;
                    if (s < rmin[slot]) { rmin[slot] = s; ridx[slot] = code; }
                }
        }
    }

    // reduce across the 16 column-lanes (tm) per row
#pragma unroll
    for (int slot = 0; slot < 16; ++slot) {
        float bv = rmin[slot];
        int   bi = ridx[slot];
#pragma unroll
        for (int m = 1; m <= 8; m <<= 1) {
            float v2 = __shfl_xor(bv, m, 64);
            int   i2 = __shfl_xor(bi, m, 64);
            if (v2 < bv || (v2 == bv && i2 < bi)) { bv = v2; bi = i2; }
        }
        if (tm == 0) {
            int grow = r0 + m0w + (slot >> 2) * 16 + q * 4 + (slot & 3);
            int part = sp * 2 + wn;
            ((float*)(ws + WS_PV))[part * MROWS + grow] = bv;
            ((int*)(ws + WS_PI))[part * MROWS + grow] = bi;
        }
    }
}

// ---------------------------------------------------------------------------
// Kernel 3: merge the NPART partials; emit indices (as float).
__global__ void merge_kernel(char* __restrict__ ws,
                             float* __restrict__ out_idx_f) {
    int r = blockIdx.x * 256 + threadIdx.x;
    const float* pv = (const float*)(ws + WS_PV);
    const int*   pi = (const int*)(ws + WS_PI);
    float bv = pv[r];
    int   bi = pi[r];
#pragma unroll
    for (int p = 1; p < NPART; ++p) {
        float v = pv[p * MROWS + r];
        int   i = pi[p * MROWS + r];
        if (v < bv || (v == bv && i < bi)) { bv = v; bi = i; }
    }
    ((int*)(ws + WS_FI))[r] = bi;
    out_idx_f[r] = (float)bi;
}

// ---------------------------------------------------------------------------
// Kernel 4: gather quantized vectors, STE output, 1.25*MSE loss.
__global__ void quant_loss_kernel(const float* __restrict__ z,
                                  const float* __restrict__ emb,
                                  const char* __restrict__ ws,
                                  float* __restrict__ out) {
    __shared__ float wsum[4];
    int f = blockIdx.x * 256 + threadIdx.x;
    int row = f >> 6, c4 = f & 63;
    int idx = ((const int*)(ws + WS_FI))[row];
    float4 qv = ((const float4*)(emb + (size_t)idx * CDIM))[c4];
    float4 zv = ((const float4*)z)[f];
    float dx = qv.x - zv.x, dy = qv.y - zv.y, dz = qv.z - zv.z, dw = qv.w - zv.w;
    float4 o;
    o.x = zv.x + dx; o.y = zv.y + dy; o.z = zv.z + dz; o.w = zv.w + dw;
    ((float4*)out)[f] = o;
    float s = dx * dx + dy * dy + dz * dz + dw * dw;
#pragma unroll
    for (int m = 32; m >= 1; m >>= 1) s += __shfl_xor(s, m, 64);
    int lane = threadIdx.x & 63, wv = threadIdx.x >> 6;
    if (lane == 0) wsum[wv] = s;
    __syncthreads();
    if (threadIdx.x == 0) {
        float t = wsum[0] + wsum[1] + wsum[2] + wsum[3];
        atomicAdd(out + LOSS_OFF, t * (1.25f / 4194304.f));
    }
}

// ---------------------------------------------------------------------------
extern "C" void kernel_launch(void* const* d_in, const int* in_sizes, int n_in,
                              void* d_out, int out_size, void* d_ws, size_t ws_size,
                              hipStream_t stream) {
    const float* z   = (const float*)d_in[0];
    const float* emb = (const float*)d_in[1];
    float* out = (float*)d_out;
    char*  ws  = (char*)d_ws;   // needs ~26.7 MB

    hipLaunchKernelGGL(split_kernel, dim3((MROWS + KCODES) * CDIM / 4 / 256),
                       dim3(256), 0, stream, z, emb, ws);
    hipLaunchKernelGGL(enorm_kernel, dim3(KCODES / 4), dim3(256), 0, stream,
                       emb, ws, out + LOSS_OFF);
    hipLaunchKernelGGL(vq_argmin_kernel, dim3((MROWS / BM) * NSPLIT), dim3(256),
                       0, stream, ws, ws);
    hipLaunchKernelGGL(merge_kernel, dim3(MROWS / 256), dim3(256), 0, stream,
                       ws, out + IDXOFF);
    hipLaunchKernelGGL(quant_loss_kernel, dim3(MROWS * CDIM / 4 / 256), dim3(256),
                       0, stream, z, emb, ws, out);
}